// Round 16
// baseline (192.812 us; speedup 1.0000x reference)
//
#include <hip/hip_runtime.h>
#include <stdint.h>

typedef _Float16 f16x8 __attribute__((ext_vector_type(8)));
typedef float f32x4 __attribute__((ext_vector_type(4)));

#define W_TOT 2048
#define CK    192

static __device__ __forceinline__ f16x8 cvt8(f32x4 a, f32x4 b) {
    f16x8 r;
    r[0] = (_Float16)a[0]; r[1] = (_Float16)a[1]; r[2] = (_Float16)a[2]; r[3] = (_Float16)a[3];
    r[4] = (_Float16)b[0]; r[5] = (_Float16)b[1]; r[6] = (_Float16)b[2]; r[7] = (_Float16)b[3];
    return r;
}

// ============ pre-pass: xP[w][b][c*3+j] = (f16) x[b][c][w-1+j], 0-padded ============
// 512 blocks = 32 b x 16 w-tiles(128). Every x cache line read exactly once (coalesced).
__global__ __launch_bounds__(256, 2)
void xp_build(const float* __restrict__ x, _Float16* __restrict__ xP) {
    __shared__ _Float16 Xt[144 * 72];   // [iw][c], stride 72 halfs (16B-aligned rows, 2-way banks)
    const int tid = threadIdx.x;
    const int b   = blockIdx.x >> 4;
    const int wt  = (blockIdx.x & 15) << 7;

    {   // load phase: lane c reads its own x row along w (coalesced per lane, line-exact)
        const int c = tid & 63, q = tid >> 6;
        const float* xr = x + ((size_t)(b * 64 + c)) * W_TOT;
        #pragma unroll
        for (int k = 0; k < 9; ++k) {
            int iw = q * 36 + k * 4;
            int wg = wt - 4 + iw;       // global w of element 0
            float v0, v1, v2, v3;
            if (wg >= 0 && wg + 3 < W_TOT) {
                float4 v = *(const float4*)(xr + wg);
                v0 = v.x; v1 = v.y; v2 = v.z; v3 = v.w;
            } else {
                v0 = (wg + 0 >= 0 && wg + 0 < W_TOT) ? xr[wg + 0] : 0.f;
                v1 = (wg + 1 >= 0 && wg + 1 < W_TOT) ? xr[wg + 1] : 0.f;
                v2 = (wg + 2 >= 0 && wg + 2 < W_TOT) ? xr[wg + 2] : 0.f;
                v3 = (wg + 3 >= 0 && wg + 3 < W_TOT) ? xr[wg + 3] : 0.f;
            }
            Xt[(iw + 0) * 72 + c] = (_Float16)v0;
            Xt[(iw + 1) * 72 + c] = (_Float16)v1;
            Xt[(iw + 2) * 72 + c] = (_Float16)v2;
            Xt[(iw + 3) * 72 + c] = (_Float16)v3;
        }
    }
    __syncthreads();
    {   // write phase: interleave 3 w-rows -> contiguous 192-half (b,w) rows of xP
        const int wp = tid >> 1, h = tid & 1;
        _Float16* ob = xP + (size_t)(wt + wp) * 6144 + b * 192 + h * 96;
        #pragma unroll
        for (int cg = 0; cg < 4; ++cg) {
            int c0 = h * 32 + cg * 8;
            f16x8 r0 = *(const f16x8*)&Xt[(wp + 3) * 72 + c0];   // j=0 (w-1)
            f16x8 r1 = *(const f16x8*)&Xt[(wp + 4) * 72 + c0];   // j=1 (w)
            f16x8 r2 = *(const f16x8*)&Xt[(wp + 5) * 72 + c0];   // j=2 (w+1)
            _Float16 t[24];
            #pragma unroll
            for (int m = 0; m < 8; ++m) { t[m*3] = r0[m]; t[m*3+1] = r1[m]; t[m*3+2] = r2[m]; }
            f16x8 o0, o1, o2;
            #pragma unroll
            for (int m = 0; m < 8; ++m) { o0[m] = t[m]; o1[m] = t[8+m]; o2[m] = t[16+m]; }
            *(f16x8*)(ob + cg * 24 + 0)  = o0;
            *(f16x8*)(ob + cg * 24 + 8)  = o1;
            *(f16x8*)(ob + cg * 24 + 16) = o2;
        }
    }
}

// ============ main: per block = 8 w x 32 o-half; all inputs DMA'd coalesced ============
static __device__ __forceinline__ void stage_w(const char* wsrc, char* ldsw,
                                               const char* xsrc, char* ldsx,
                                               int wv, int lane) {
    #pragma unroll
    for (int i = 0; i < 6; ++i) {            // 24 KB weight half-panel (f32)
        int d = wv * 6144 + i * 1024 + lane * 16;
        int r = d / 768;                      // 768 B per o-row
        __builtin_amdgcn_global_load_lds(
            (const __attribute__((address_space(1))) uint32_t*)(wsrc + (d ^ ((r & 7) << 4))),
            (__attribute__((address_space(3))) uint32_t*)(ldsw + d), 16, 0, 0);
    }
    #pragma unroll
    for (int i = 0; i < 3; ++i) {            // 12 KB patch (f16)
        int d = wv * 3072 + i * 1024 + lane * 16;
        int r = d / 384;                      // 384 B per b-row
        __builtin_amdgcn_global_load_lds(
            (const __attribute__((address_space(1))) uint32_t*)(xsrc + (d ^ ((r & 7) << 4))),
            (__attribute__((address_space(3))) uint32_t*)(ldsx + d), 16, 0, 0);
    }
}

static __device__ __forceinline__ void compute_w(const char* wrow, const char* xrow,
                                                 int kg, int sm, int smx, f32x4& acc) {
    #pragma unroll
    for (int ks = 0; ks < 6; ++ks) {
        f32x4 b0 = *(const f32x4*)(wrow + (((ks * 128 + kg * 32) + 0)  ^ sm));
        f32x4 b1 = *(const f32x4*)(wrow + (((ks * 128 + kg * 32) + 16) ^ sm));
        f16x8 bw = cvt8(b0, b1);
        f16x8 a  = *(const f16x8*)(xrow + ((ks * 64 + kg * 16) ^ smx));
        acc = __builtin_amdgcn_mfma_f32_16x16x32_f16(a, bw, acc, 0, 0, 0);
    }
}

__global__ __launch_bounds__(256, 2)
void lc1d_main(const _Float16* __restrict__ xP,
               const float* __restrict__ wts,
               const float* __restrict__ bias,
               float* __restrict__ out) {
    __shared__ char WfL[2][24576];   // f32 weights, XOR-swizzled storage
    __shared__ char XpL[2][12288];   // f16 patch,   XOR-swizzled storage (73.7 KB total)

    const int tid = threadIdx.x;
    const int bid = blockIdx.x;
    const int xcd = bid & 7, idx = bid >> 3;
    const int wc  = xcd * 32 + (idx >> 1);   // XCD-contiguous w-chunks; o-half pairs share XCD
    const int bo  = idx & 1;                 // o-half
    const int w0  = wc * 8;

    const int lane = tid & 63, wv = tid >> 6;
    const int bt = wv >> 1, ot = wv & 1;     // wave = (b-tile, o-tile)
    const int l15 = lane & 15, kg = lane >> 4;
    const int o_loc = ot * 16 + l15;
    const int o = bo * 32 + o_loc;
    const int sm  = (o_loc & 7) << 4;
    const int smx = (l15 & 7) << 4;

    const char* wgbase = (const char*)wts + (size_t)w0 * 49152 + (size_t)bo * 24576;
    const char* xgbase = (const char*)xP + (size_t)w0 * 12288;
    const char* wrow = &WfL[0][0] + o_loc * 768;
    const char* xrow = &XpL[0][0] + (bt * 16 + l15) * 384;
    const int BUF1W = 24576, BUF1X = 12288;  // byte offset of buffer 1

    stage_w(wgbase, &WfL[0][0], xgbase, &XpL[0][0], wv, lane);
    const f32x4 bg0 = *(const f32x4*)(bias + (size_t)o * W_TOT + w0);
    const f32x4 bg1 = *(const f32x4*)(bias + (size_t)o * W_TOT + w0 + 4);
    __syncthreads();

    f32x4 a0 = {0.f,0.f,0.f,0.f}, a1 = a0, a2 = a0, a3 = a0;

    // group 0: w0..w0+3
    stage_w(wgbase + 1*49152, &WfL[0][0]+BUF1W, xgbase + 1*12288, &XpL[0][0]+BUF1X, wv, lane);
    compute_w(wrow,          xrow,          kg, sm, smx, a0);  __syncthreads();
    stage_w(wgbase + 2*49152, &WfL[0][0],   xgbase + 2*12288, &XpL[0][0],          wv, lane);
    compute_w(wrow + BUF1W,  xrow + BUF1X,  kg, sm, smx, a1);  __syncthreads();
    stage_w(wgbase + 3*49152, &WfL[0][0]+BUF1W, xgbase + 3*12288, &XpL[0][0]+BUF1X, wv, lane);
    compute_w(wrow,          xrow,          kg, sm, smx, a2);  __syncthreads();
    stage_w(wgbase + 4*49152, &WfL[0][0],   xgbase + 4*12288, &XpL[0][0],          wv, lane);
    compute_w(wrow + BUF1W,  xrow + BUF1X,  kg, sm, smx, a3);
    #pragma unroll
    for (int r = 0; r < 4; ++r) {
        f32x4 v = { a0[r] + bg0[0], a1[r] + bg0[1], a2[r] + bg0[2], a3[r] + bg0[3] };
        *(f32x4*)(out + ((size_t)((bt * 16 + kg * 4 + r) * 64 + o)) * W_TOT + w0) = v;
    }
    __syncthreads();

    // group 1: w0+4..w0+7
    a0 = {0.f,0.f,0.f,0.f}; a1 = a0; a2 = a0; a3 = a0;
    stage_w(wgbase + 5*49152, &WfL[0][0]+BUF1W, xgbase + 5*12288, &XpL[0][0]+BUF1X, wv, lane);
    compute_w(wrow,          xrow,          kg, sm, smx, a0);  __syncthreads();
    stage_w(wgbase + 6*49152, &WfL[0][0],   xgbase + 6*12288, &XpL[0][0],          wv, lane);
    compute_w(wrow + BUF1W,  xrow + BUF1X,  kg, sm, smx, a1);  __syncthreads();
    stage_w(wgbase + 7*49152, &WfL[0][0]+BUF1W, xgbase + 7*12288, &XpL[0][0]+BUF1X, wv, lane);
    compute_w(wrow,          xrow,          kg, sm, smx, a2);  __syncthreads();
    compute_w(wrow + BUF1W,  xrow + BUF1X,  kg, sm, smx, a3);
    #pragma unroll
    for (int r = 0; r < 4; ++r) {
        f32x4 v = { a0[r] + bg1[0], a1[r] + bg1[1], a2[r] + bg1[2], a3[r] + bg1[3] };
        *(f32x4*)(out + ((size_t)((bt * 16 + kg * 4 + r) * 64 + o)) * W_TOT + w0 + 4) = v;
    }
}

extern "C" void kernel_launch(void* const* d_in, const int* in_sizes, int n_in,
                              void* d_out, int out_size, void* d_ws, size_t ws_size,
                              hipStream_t stream) {
    const float* x    = (const float*)d_in[0];
    const float* wts  = (const float*)d_in[1];
    const float* bias = (const float*)d_in[2];
    float* out = (float*)d_out;
    _Float16* xP = (_Float16*)d_ws;   // 2048*32*192*2 B = 25.2 MB scratch
    hipLaunchKernelGGL(xp_build, dim3(512), dim3(256), 0, stream, x, xP);
    hipLaunchKernelGGL(lc1d_main, dim3(512), dim3(256), 0, stream, xP, wts, bias, out);
}